// Round 7
// baseline (624.888 us; speedup 1.0000x reference)
//
#include <hip/hip_runtime.h>

// ---------------------------------------------------------------------------
// 3-layer GCN. Edges are bucketed by dst-window once (phase1, counting-sort
// into a fixed per-bucket arena, dense packed writes). No per-node sort:
// the gather consumes each bucket's packed (src, local-dst) pairs directly
// and reduces into an LDS accumulator tile [196 x F] with ds_add_f32, then
// writes the contiguous node window with a fused dinv/bias/relu epilogue.
// dinv comes from a per-bucket LDS histogram over the same pairs.
// ---------------------------------------------------------------------------

#define NB   256            // buckets per layer (window W = ceil(n/NB) = 196 < 512)
#define NL   3
#define TB   (NB * NL)      // 768 buckets
#define CAPE 6400           // arena capacity per bucket (mean fill ~3125)
#define CH   4096           // edges per phase-1 chunk
#define P1T  512
#define EPT  (CH / P1T)     // 8 edges per thread, held in registers
#define WMAX 200            // >= W

__device__ __forceinline__ void decode_chunk(int g, int nc1, int nc2,
                                             const int* s1, const int* d1, int E1,
                                             const int* s2, const int* d2, int E2,
                                             const int* s3, const int* d3, int E3,
                                             const int** src, const int** dst, int* E, int* l,
                                             int* gout) {
    if (g < nc1)            { *src = s1; *dst = d1; *E = E1; *l = 0; }
    else if (g < nc1 + nc2) { *src = s2; *dst = d2; *E = E2; *l = 1; g -= nc1; }
    else                    { *src = s3; *dst = d3; *E = E3; *l = 2; g -= nc1 + nc2; }
    *gout = g;
}

__global__ void __launch_bounds__(P1T) phase1(
        const int* __restrict__ s1, const int* __restrict__ d1, int E1,
        const int* __restrict__ s2, const int* __restrict__ d2, int E2,
        const int* __restrict__ s3, const int* __restrict__ d3, int E3,
        int nc1, int nc2, int W,
        int* __restrict__ gcur, unsigned int* __restrict__ pairBuf) {
    __shared__ int hist[TB];
    __shared__ int bo[TB];
    __shared__ int lcur[TB];
    for (int i = threadIdx.x; i < TB; i += P1T) hist[i] = 0;
    __syncthreads();

    const int* src; const int* dst; int E, l, g;
    decode_chunk(blockIdx.x, nc1, nc2, s1, d1, E1, s2, d2, E2, s3, d3, E3,
                 &src, &dst, &E, &l, &g);
    const int e0 = g * CH;
    const int lbase = l * NB;

    unsigned pv[EPT];
    int bn[EPT];
    if (E - e0 >= CH) {                       // full chunk: int4 register loads
        const int4* s4 = (const int4*)(src + e0);
        const int4* d4 = (const int4*)(dst + e0);
#pragma unroll
        for (int w = 0; w < EPT / 4; ++w) {
            int4 sv = s4[threadIdx.x + w * P1T];
            int4 dv = d4[threadIdx.x + w * P1T];
            int q, i = w * 4;
            q = dv.x / W; bn[i+0] = lbase + q; pv[i+0] = ((unsigned)sv.x << 9) | (unsigned)(dv.x - q * W);
            q = dv.y / W; bn[i+1] = lbase + q; pv[i+1] = ((unsigned)sv.y << 9) | (unsigned)(dv.y - q * W);
            q = dv.z / W; bn[i+2] = lbase + q; pv[i+2] = ((unsigned)sv.z << 9) | (unsigned)(dv.z - q * W);
            q = dv.w / W; bn[i+3] = lbase + q; pv[i+3] = ((unsigned)sv.w << 9) | (unsigned)(dv.w - q * W);
        }
    } else {                                   // tail chunk: guarded scalar loads
#pragma unroll
        for (int i = 0; i < EPT; ++i) {
            int e = e0 + threadIdx.x + i * P1T;
            if (e < E) {
                int s = src[e], d = dst[e];
                int q = d / W;
                bn[i] = lbase + q;
                pv[i] = ((unsigned)s << 9) | (unsigned)(d - q * W);
            } else bn[i] = -1;
        }
    }
#pragma unroll
    for (int i = 0; i < EPT; ++i)
        if (bn[i] >= 0) atomicAdd(&hist[bn[i]], 1);
    __syncthreads();
    for (int i = threadIdx.x; i < TB; i += P1T) {
        int c = hist[i];
        bo[i] = i * CAPE + (c ? atomicAdd(&gcur[i], c) : 0);
        lcur[i] = 0;
    }
    __syncthreads();
#pragma unroll
    for (int i = 0; i < EPT; ++i) {
        if (bn[i] >= 0) {
            int r = atomicAdd(&lcur[bn[i]], 1);
            int pos = bo[bn[i]] + r;
            if (pos < (bn[i] + 1) * CAPE) pairBuf[pos] = pv[i];  // overflow guard
        }
    }
}

// Per-bucket LDS histogram of local dst -> dinv for all 3 layers.
__global__ void __launch_bounds__(256) count_dinv(
        const unsigned int* __restrict__ pairBuf, const int* __restrict__ gcur,
        int n, int W, float* __restrict__ dinv) {
    __shared__ int lcnt[512];
    const int bid = blockIdx.x;
    const int l = bid / NB, k = bid % NB;
    const int lo = k * W;
    const int hi = min(n, lo + W);
    const int Wn = hi - lo;
    const int segE = min(gcur[bid], CAPE);
    const size_t base = (size_t)bid * CAPE;
    for (int i = threadIdx.x; i < 512; i += 256) lcnt[i] = 0;
    __syncthreads();
    for (int i = threadIdx.x; i < segE; i += 256)
        atomicAdd(&lcnt[pairBuf[base + i] & 511u], 1);
    __syncthreads();
    for (int i = threadIdx.x; i < Wn; i += 256)
        dinv[(size_t)l * n + lo + i] = rsqrtf((float)lcnt[i] + 1.0f);  // +1 self-loop
}

__device__ __forceinline__ void fma4(float4& a, float s, const float4& w) {
    a.x += s * w.x; a.y += s * w.y; a.z += s * w.z; a.w += s * w.w;
}

// Register-tiled GEMM: h[row,:] = dinv[row] * (x[row,:] @ W).
template <int K, int F>
__global__ void __launch_bounds__(256) gemm_scale_kernel(
        const float* __restrict__ x, const float* __restrict__ Wg,
        const float* __restrict__ dinv, float* __restrict__ h, int n) {
    constexpr int TC  = F / 4;
    constexpr int TR  = 256 / TC;
    constexpr int BR  = 64;
    constexpr int RPT = BR / TR;
    __shared__ float Ws[K * F];
    for (int i = threadIdx.x; i < K * F / 4; i += 256)
        ((float4*)Ws)[i] = ((const float4*)Wg)[i];
    __syncthreads();
    const int tc = threadIdx.x % TC;
    const int tr = threadIdx.x / TC;
    const int row0 = blockIdx.x * BR + tr * RPT;
    const float4* x4 = (const float4*)x;
    const float4* Ws4 = (const float4*)Ws;
    float4 acc[RPT];
#pragma unroll
    for (int r = 0; r < RPT; ++r) acc[r] = make_float4(0.f, 0.f, 0.f, 0.f);
    int rowc[RPT];
#pragma unroll
    for (int r = 0; r < RPT; ++r) rowc[r] = min(row0 + r, n - 1);

    for (int k0 = 0; k0 < K; k0 += 4) {
        float4 wv0 = Ws4[(k0 + 0) * TC + tc];
        float4 wv1 = Ws4[(k0 + 1) * TC + tc];
        float4 wv2 = Ws4[(k0 + 2) * TC + tc];
        float4 wv3 = Ws4[(k0 + 3) * TC + tc];
#pragma unroll
        for (int r = 0; r < RPT; ++r) {
            float4 xv = x4[(size_t)rowc[r] * (K / 4) + (k0 / 4)];
            fma4(acc[r], xv.x, wv0);
            fma4(acc[r], xv.y, wv1);
            fma4(acc[r], xv.z, wv2);
            fma4(acc[r], xv.w, wv3);
        }
    }
    float4* h4 = (float4*)h;
#pragma unroll
    for (int r = 0; r < RPT; ++r) {
        int row = row0 + r;
        if (row < n) {
            float di = dinv[row];
            float4 o;
            o.x = acc[r].x * di; o.y = acc[r].y * di;
            o.z = acc[r].z * di; o.w = acc[r].w * di;
            h4[(size_t)row * TC + tc] = o;
        }
    }
}

// One wg per bucket: stream packed pairs, accumulate h'[src] rows into an
// LDS tile acc[W x F] via ds_add_f32, then fused epilogue over the node
// window (self-loop + bias + relu), coalesced float4 writes.
template <int F>
__global__ void __launch_bounds__(512) gather_lds(
        const unsigned int* __restrict__ pairBuf, const int* __restrict__ gcur,
        const float* __restrict__ dinv, const float* __restrict__ h,
        const float* __restrict__ b, float* __restrict__ out,
        int n, int W, int layer) {
    constexpr int VPN = F / 4;          // lanes per edge-group
    constexpr int G   = 512 / VPN;      // edge-groups per block
    __shared__ float acc[WMAX * F];
    const int bid = layer * NB + blockIdx.x;
    const int lo = blockIdx.x * W;
    const int hi = min(n, lo + W);
    const int Wn = hi - lo;
    const int segE = min(gcur[bid], CAPE);
    const size_t base = (size_t)bid * CAPE;
    for (int i = threadIdx.x; i < WMAX * F; i += 512) acc[i] = 0.f;
    __syncthreads();

    const int g  = threadIdx.x / VPN;
    const int f4 = threadIdx.x % VPN;
    const float4* h4 = (const float4*)h;
    const uint4* p4 = (const uint4*)(pairBuf + base);   // base = bid*CAPE, 4-aligned
    const int quads = segE >> 2;
    for (int q = g; q < quads; q += G) {
        uint4 pv = p4[q];
        // 4 independent row loads in flight
        float4 v0 = h4[(size_t)(pv.x >> 9) * VPN + f4];
        float4 v1 = h4[(size_t)(pv.y >> 9) * VPN + f4];
        float4 v2 = h4[(size_t)(pv.z >> 9) * VPN + f4];
        float4 v3 = h4[(size_t)(pv.w >> 9) * VPN + f4];
        float* a0 = &acc[(pv.x & 511u) * F + f4 * 4];
        float* a1 = &acc[(pv.y & 511u) * F + f4 * 4];
        float* a2 = &acc[(pv.z & 511u) * F + f4 * 4];
        float* a3 = &acc[(pv.w & 511u) * F + f4 * 4];
        atomicAdd(a0 + 0, v0.x); atomicAdd(a0 + 1, v0.y); atomicAdd(a0 + 2, v0.z); atomicAdd(a0 + 3, v0.w);
        atomicAdd(a1 + 0, v1.x); atomicAdd(a1 + 1, v1.y); atomicAdd(a1 + 2, v1.z); atomicAdd(a1 + 3, v1.w);
        atomicAdd(a2 + 0, v2.x); atomicAdd(a2 + 1, v2.y); atomicAdd(a2 + 2, v2.z); atomicAdd(a2 + 3, v2.w);
        atomicAdd(a3 + 0, v3.x); atomicAdd(a3 + 1, v3.y); atomicAdd(a3 + 2, v3.z); atomicAdd(a3 + 3, v3.w);
    }
    const int tail = segE & 3;
    if (g < tail) {
        unsigned p = pairBuf[base + quads * 4 + g];
        float4 v = h4[(size_t)(p >> 9) * VPN + f4];
        float* a = &acc[(p & 511u) * F + f4 * 4];
        atomicAdd(a + 0, v.x); atomicAdd(a + 1, v.y); atomicAdd(a + 2, v.z); atomicAdd(a + 3, v.w);
    }
    __syncthreads();

    const float4* b4 = (const float4*)b;
    float4* out4 = (float4*)out;
    const float* dl = dinv + (size_t)layer * n;
    for (int idx = threadIdx.x; idx < Wn * VPN; idx += 512) {
        int nl = idx / VPN, f = idx % VPN;
        int node = lo + nl;
        float4 a = *(const float4*)&acc[nl * F + f * 4];
        float4 self = h4[(size_t)node * VPN + f];
        float4 bv = b4[f];
        float di = dl[node];
        float4 o;
        o.x = di * (a.x + self.x) + bv.x;
        o.y = di * (a.y + self.y) + bv.y;
        o.z = di * (a.z + self.z) + bv.z;
        o.w = di * (a.w + self.w) + bv.w;
        o.x = o.x > 0.f ? o.x : 0.f;
        o.y = o.y > 0.f ? o.y : 0.f;
        o.z = o.z > 0.f ? o.z : 0.f;
        o.w = o.w > 0.f ? o.w : 0.f;
        out4[(size_t)node * VPN + f] = o;
    }
}

extern "C" void kernel_launch(void* const* d_in, const int* in_sizes, int n_in,
                              void* d_out, int out_size, void* d_ws, size_t ws_size,
                              hipStream_t stream) {
    const float* x0  = (const float*)d_in[0];
    const int*   ei1 = (const int*)d_in[1];
    const int*   ei3 = (const int*)d_in[2];
    const int*   ei9 = (const int*)d_in[3];
    const float* W1  = (const float*)d_in[4];
    const float* b1  = (const float*)d_in[5];
    const float* W2  = (const float*)d_in[6];
    const float* b2  = (const float*)d_in[7];
    const float* W3  = (const float*)d_in[8];
    const float* b3  = (const float*)d_in[9];

    const int n  = in_sizes[0] / 64;  // 50000
    const int E1 = in_sizes[1] / 2;   // 800000
    const int E3 = in_sizes[2] / 2;
    const int E9 = in_sizes[3] / 2;
    const int W  = (n + NB - 1) / NB; // 196 (< 512 -> 9-bit local id)

    const int nc1 = (E1 + CH - 1) / CH;
    const int nc2 = (E3 + CH - 1) / CH;
    const int nc3 = (E9 + CH - 1) / CH;
    const int nchunks = nc1 + nc2 + nc3;

    int* gcur    = (int*)d_ws;                           // TB
    unsigned int* pairBuf = (unsigned int*)(gcur + TB);  // TB*CAPE
    float* dinv  = (float*)(pairBuf + (size_t)TB * CAPE);// 3n
    float* h     = dinv + (size_t)3 * n;                 // n*64
    float* x1    = h + (size_t)n * 64;                   // n*64
    float* x2    = x1 + (size_t)n * 64;                  // n*32

    // ---- bucket sort + degrees (all 3 layers) ----
    hipMemsetAsync(gcur, 0, TB * sizeof(int), stream);
    phase1<<<nchunks, P1T, 0, stream>>>(ei1, ei1 + E1, E1, ei3, ei3 + E3, E3,
                                        ei9, ei9 + E9, E9, nc1, nc2, W, gcur, pairBuf);
    count_dinv<<<TB, 256, 0, stream>>>(pairBuf, gcur, n, W, dinv);

    const int gblk = (n + 63) / 64;

    // ---- layer 1: 64 -> 64 ----
    gemm_scale_kernel<64, 64><<<gblk, 256, 0, stream>>>(x0, W1, dinv, h, n);
    gather_lds<64><<<NB, 512, 0, stream>>>(pairBuf, gcur, dinv, h, b1, x1, n, W, 0);

    // ---- layer 2: 64 -> 32 ----
    gemm_scale_kernel<64, 32><<<gblk, 256, 0, stream>>>(x1, W2, dinv + n, h, n);
    gather_lds<32><<<NB, 512, 0, stream>>>(pairBuf, gcur, dinv, h, b2, x2, n, W, 1);

    // ---- layer 3: 32 -> 16 ----
    gemm_scale_kernel<32, 16><<<gblk, 256, 0, stream>>>(x2, W3, dinv + 2 * n, h, n);
    gather_lds<16><<<NB, 512, 0, stream>>>(pairBuf, gcur, dinv, h, b3, (float*)d_out, n, W, 2);
}

// Round 8
// 217.993 us; speedup vs baseline: 2.8665x; 2.8665x over previous
//
#include <hip/hip_runtime.h>

// ---------------------------------------------------------------------------
// 3-layer GCN, gather formulation. CSR built by a 2-kernel counting sort:
//   phase1: per-wg chunk of 8192 edges held in registers; LDS (int) hist ->
//           one global atomic per (wg,bucket) reserves a contiguous run in
//           bucket's fixed arena region (bid*CAPE) -> dense packed writes.
//   phase2: one wg per bucket; LDS (int) hist of its 196-node window ->
//           x4-padded scan gives row_ptr/cnt/dinv; places srcs via LDS
//           staging, streams eidx out coalesced (int4).
// Gather reads edge ids as aligned int4 (segments start at multiples of 4)
// with 16 edges in flight; h rows as float4.
// NOTE (R6 post-mortem): f32 LDS atomicAdd is a serializing slow path on
// gfx950 (~300cyc/op measured) — int LDS atomics are fast. Never aggregate
// floats through LDS atomics.
// ---------------------------------------------------------------------------

#define NB   256            // buckets per layer (W = ceil(n/NB) = 196 < 512)
#define NL   3
#define TB   (NB * NL)      // 768 buckets
#define CAPE 6400           // arena capacity per bucket (mean fill ~3125)
#define CH   8192           // edges per phase-1 chunk
#define P1T  512
#define EPT  (CH / P1T)     // 16 edges per thread, held in registers
#define P2T  512
#define CAP2 CAPE           // phase-2 LDS staging capacity

__device__ __forceinline__ void decode_chunk(int g, int nc1, int nc2,
                                             const int* s1, const int* d1, int E1,
                                             const int* s2, const int* d2, int E2,
                                             const int* s3, const int* d3, int E3,
                                             const int** src, const int** dst, int* E, int* l,
                                             int* gout) {
    if (g < nc1)            { *src = s1; *dst = d1; *E = E1; *l = 0; }
    else if (g < nc1 + nc2) { *src = s2; *dst = d2; *E = E2; *l = 1; g -= nc1; }
    else                    { *src = s3; *dst = d3; *E = E3; *l = 2; g -= nc1 + nc2; }
    *gout = g;
}

__global__ void __launch_bounds__(P1T) phase1(
        const int* __restrict__ s1, const int* __restrict__ d1, int E1,
        const int* __restrict__ s2, const int* __restrict__ d2, int E2,
        const int* __restrict__ s3, const int* __restrict__ d3, int E3,
        int nc1, int nc2, int W,
        int* __restrict__ gcur, unsigned int* __restrict__ pairBuf) {
    __shared__ int hist[TB];
    __shared__ int bo[TB];
    __shared__ int lcur[TB];
    for (int i = threadIdx.x; i < TB; i += P1T) hist[i] = 0;
    __syncthreads();

    const int* src; const int* dst; int E, l, g;
    decode_chunk(blockIdx.x, nc1, nc2, s1, d1, E1, s2, d2, E2, s3, d3, E3,
                 &src, &dst, &E, &l, &g);
    const int e0 = g * CH;
    const int lbase = l * NB;

    unsigned pv[EPT];
    int bn[EPT];
    if (E - e0 >= CH) {                       // full chunk: int4 register loads
        const int4* s4 = (const int4*)(src + e0);
        const int4* d4 = (const int4*)(dst + e0);
#pragma unroll
        for (int w = 0; w < EPT / 4; ++w) {
            int4 sv = s4[threadIdx.x + w * P1T];
            int4 dv = d4[threadIdx.x + w * P1T];
            int q, i = w * 4;
            q = dv.x / W; bn[i+0] = lbase + q; pv[i+0] = ((unsigned)sv.x << 9) | (unsigned)(dv.x - q * W);
            q = dv.y / W; bn[i+1] = lbase + q; pv[i+1] = ((unsigned)sv.y << 9) | (unsigned)(dv.y - q * W);
            q = dv.z / W; bn[i+2] = lbase + q; pv[i+2] = ((unsigned)sv.z << 9) | (unsigned)(dv.z - q * W);
            q = dv.w / W; bn[i+3] = lbase + q; pv[i+3] = ((unsigned)sv.w << 9) | (unsigned)(dv.w - q * W);
        }
    } else {                                   // tail chunk: guarded scalar loads
#pragma unroll
        for (int i = 0; i < EPT; ++i) {
            int e = e0 + threadIdx.x + i * P1T;
            if (e < E) {
                int s = src[e], d = dst[e];
                int q = d / W;
                bn[i] = lbase + q;
                pv[i] = ((unsigned)s << 9) | (unsigned)(d - q * W);
            } else bn[i] = -1;
        }
    }
#pragma unroll
    for (int i = 0; i < EPT; ++i)
        if (bn[i] >= 0) atomicAdd(&hist[bn[i]], 1);
    __syncthreads();
    for (int i = threadIdx.x; i < TB; i += P1T) {
        int c = hist[i];
        bo[i] = i * CAPE + (c ? atomicAdd(&gcur[i], c) : 0);
        lcur[i] = 0;
    }
    __syncthreads();
#pragma unroll
    for (int i = 0; i < EPT; ++i) {
        if (bn[i] >= 0) {
            int r = atomicAdd(&lcur[bn[i]], 1);
            int pos = bo[bn[i]] + r;
            if (pos < (bn[i] + 1) * CAPE) pairBuf[pos] = pv[i];  // overflow guard
        }
    }
}

// One wg per bucket: LDS hist -> padded scan -> row_ptr/cnt/dinv, place srcs,
// coalesced int4 output.  Segment starts aligned to 4 for gather int4 loads.
__global__ void __launch_bounds__(P2T) phase2(
        const unsigned int* __restrict__ pairBuf, const int* __restrict__ gcur,
        int n, int W,
        int* __restrict__ row_ptr, int* __restrict__ cnt_g,
        float* __restrict__ dinv, int* __restrict__ eidx) {
    __shared__ int lcnt[P2T];
    __shared__ int lscan[P2T];
    __shared__ int stage[CAP2];
    const int bid = blockIdx.x;
    const int l = bid / NB, k = bid % NB;
    const int lo = k * W;
    const int hi = min(n, lo + W);
    const int Wn = hi - lo;                 // <= 196 < P2T
    const int segE = min(gcur[bid], CAPE);
    const size_t base = (size_t)bid * CAPE;
    const int t = threadIdx.x;
    lcnt[t] = 0;
    __syncthreads();
    for (int i = t; i < segE; i += P2T)
        atomicAdd(&lcnt[pairBuf[base + i] & 511u], 1);
    __syncthreads();
    const int v = lcnt[t];
    const int vp = (v + 3) & ~3;            // pad each segment to x4
    lscan[t] = vp;
    __syncthreads();
    for (int off = 1; off < P2T; off <<= 1) {
        int add = (t >= off) ? lscan[t - off] : 0;
        __syncthreads();
        lscan[t] += add;
        __syncthreads();
    }
    const int pexcl = lscan[t] - vp;
    const int segEp = lscan[P2T - 1];       // padded total
    if (t < Wn) {
        int node = l * n + lo + t;
        row_ptr[node] = (int)base + pexcl;  // base % 4 == 0, pexcl % 4 == 0
        cnt_g[node] = v;
        dinv[node] = rsqrtf((float)v + 1.0f);   // +1 self-loop
    }
    __syncthreads();
    lcnt[t] = pexcl;                        // placement cursors
    __syncthreads();
    const bool lds_ok = (segEp <= CAP2);
    for (int i = t; i < segE; i += P2T) {
        unsigned p = pairBuf[base + i];
        int pos = atomicAdd(&lcnt[p & 511u], 1);
        int s = (int)(p >> 9);
        if (lds_ok) stage[pos] = s;
        else if (pos < CAPE) eidx[base + pos] = s;
    }
    __syncthreads();
    if (lds_ok) {
        const int4* st4 = (const int4*)stage;
        int4* e4 = (int4*)(eidx + base);
        int m4 = segEp >> 2;
        for (int i = t; i < m4; i += P2T) e4[i] = st4[i];
    }
}

__device__ __forceinline__ void fma4(float4& a, float s, const float4& w) {
    a.x += s * w.x; a.y += s * w.y; a.z += s * w.z; a.w += s * w.w;
}
__device__ __forceinline__ void add4(float4& a, const float4& v) {
    a.x += v.x; a.y += v.y; a.z += v.z; a.w += v.w;
}

// Register-tiled GEMM: h[row,:] = dinv[row] * (x[row,:] @ W).
template <int K, int F>
__global__ void __launch_bounds__(256) gemm_scale_kernel(
        const float* __restrict__ x, const float* __restrict__ Wg,
        const float* __restrict__ dinv, float* __restrict__ h, int n) {
    constexpr int TC  = F / 4;
    constexpr int TR  = 256 / TC;
    constexpr int BR  = 64;
    constexpr int RPT = BR / TR;
    __shared__ float Ws[K * F];
    for (int i = threadIdx.x; i < K * F / 4; i += 256)
        ((float4*)Ws)[i] = ((const float4*)Wg)[i];
    __syncthreads();
    const int tc = threadIdx.x % TC;
    const int tr = threadIdx.x / TC;
    const int row0 = blockIdx.x * BR + tr * RPT;
    const float4* x4 = (const float4*)x;
    const float4* Ws4 = (const float4*)Ws;
    float4 acc[RPT];
#pragma unroll
    for (int r = 0; r < RPT; ++r) acc[r] = make_float4(0.f, 0.f, 0.f, 0.f);
    int rowc[RPT];
#pragma unroll
    for (int r = 0; r < RPT; ++r) rowc[r] = min(row0 + r, n - 1);

    for (int k0 = 0; k0 < K; k0 += 4) {
        float4 wv0 = Ws4[(k0 + 0) * TC + tc];
        float4 wv1 = Ws4[(k0 + 1) * TC + tc];
        float4 wv2 = Ws4[(k0 + 2) * TC + tc];
        float4 wv3 = Ws4[(k0 + 3) * TC + tc];
#pragma unroll
        for (int r = 0; r < RPT; ++r) {
            float4 xv = x4[(size_t)rowc[r] * (K / 4) + (k0 / 4)];
            fma4(acc[r], xv.x, wv0);
            fma4(acc[r], xv.y, wv1);
            fma4(acc[r], xv.z, wv2);
            fma4(acc[r], xv.w, wv3);
        }
    }
    float4* h4 = (float4*)h;
#pragma unroll
    for (int r = 0; r < RPT; ++r) {
        int row = row0 + r;
        if (row < n) {
            float di = dinv[row];
            float4 o;
            o.x = acc[r].x * di; o.y = acc[r].y * di;
            o.z = acc[r].z * di; o.w = acc[r].w * di;
            h4[(size_t)row * TC + tc] = o;
        }
    }
}

// float4 gather, int4 edge-id loads (segments 4-aligned), 16 edges in flight.
template <int F>
__global__ void gather_kernel(const int* __restrict__ row_ptr, const int* __restrict__ cnt,
                              const int* __restrict__ eidx, const float* __restrict__ dinv,
                              const float* __restrict__ h, const float* __restrict__ b,
                              float* __restrict__ out, int n) {
    constexpr int VPN = F / 4;
    constexpr int NPB = 256 / VPN;
    const int node = blockIdx.x * NPB + (int)(threadIdx.x / VPN);
    const int f4 = threadIdx.x % VPN;
    if (node >= n) return;
    const int beg = row_ptr[node];          // multiple of 4
    const int m = cnt[node];
    const float4* h4 = (const float4*)h;
    float4 a0 = make_float4(0.f, 0.f, 0.f, 0.f), a1 = a0, a2 = a0, a3 = a0;
    int j = 0;
    for (; j + 16 <= m; j += 16) {
        int4 e0 = *(const int4*)(eidx + beg + j);
        int4 e1 = *(const int4*)(eidx + beg + j + 4);
        int4 e2 = *(const int4*)(eidx + beg + j + 8);
        int4 e3 = *(const int4*)(eidx + beg + j + 12);
        float4 v0 = h4[(size_t)e0.x * VPN + f4];
        float4 v1 = h4[(size_t)e0.y * VPN + f4];
        float4 v2 = h4[(size_t)e0.z * VPN + f4];
        float4 v3 = h4[(size_t)e0.w * VPN + f4];
        float4 v4 = h4[(size_t)e1.x * VPN + f4];
        float4 v5 = h4[(size_t)e1.y * VPN + f4];
        float4 v6 = h4[(size_t)e1.z * VPN + f4];
        float4 v7 = h4[(size_t)e1.w * VPN + f4];
        float4 v8 = h4[(size_t)e2.x * VPN + f4];
        float4 v9 = h4[(size_t)e2.y * VPN + f4];
        float4 va = h4[(size_t)e2.z * VPN + f4];
        float4 vb = h4[(size_t)e2.w * VPN + f4];
        float4 vc = h4[(size_t)e3.x * VPN + f4];
        float4 vd = h4[(size_t)e3.y * VPN + f4];
        float4 ve = h4[(size_t)e3.z * VPN + f4];
        float4 vf = h4[(size_t)e3.w * VPN + f4];
        add4(a0, v0); add4(a1, v1); add4(a2, v2); add4(a3, v3);
        add4(a0, v4); add4(a1, v5); add4(a2, v6); add4(a3, v7);
        add4(a0, v8); add4(a1, v9); add4(a2, va); add4(a3, vb);
        add4(a0, vc); add4(a1, vd); add4(a2, ve); add4(a3, vf);
    }
    for (; j + 4 <= m; j += 4) {
        int4 e0 = *(const int4*)(eidx + beg + j);
        add4(a0, h4[(size_t)e0.x * VPN + f4]);
        add4(a1, h4[(size_t)e0.y * VPN + f4]);
        add4(a2, h4[(size_t)e0.z * VPN + f4]);
        add4(a3, h4[(size_t)e0.w * VPN + f4]);
    }
    for (; j < m; ++j) add4(a0, h4[(size_t)eidx[beg + j] * VPN + f4]);
    add4(a0, a1); add4(a2, a3); add4(a0, a2);
    float4 self = h4[(size_t)node * VPN + f4];
    float4 bv = ((const float4*)b)[f4];
    float di = dinv[node];
    float4 o;
    o.x = di * (a0.x + self.x) + bv.x;
    o.y = di * (a0.y + self.y) + bv.y;
    o.z = di * (a0.z + self.z) + bv.z;
    o.w = di * (a0.w + self.w) + bv.w;
    o.x = o.x > 0.f ? o.x : 0.f;
    o.y = o.y > 0.f ? o.y : 0.f;
    o.z = o.z > 0.f ? o.z : 0.f;
    o.w = o.w > 0.f ? o.w : 0.f;
    ((float4*)out)[(size_t)node * VPN + f4] = o;
}

extern "C" void kernel_launch(void* const* d_in, const int* in_sizes, int n_in,
                              void* d_out, int out_size, void* d_ws, size_t ws_size,
                              hipStream_t stream) {
    const float* x0  = (const float*)d_in[0];
    const int*   ei1 = (const int*)d_in[1];
    const int*   ei3 = (const int*)d_in[2];
    const int*   ei9 = (const int*)d_in[3];
    const float* W1  = (const float*)d_in[4];
    const float* b1  = (const float*)d_in[5];
    const float* W2  = (const float*)d_in[6];
    const float* b2  = (const float*)d_in[7];
    const float* W3  = (const float*)d_in[8];
    const float* b3  = (const float*)d_in[9];

    const int n  = in_sizes[0] / 64;  // 50000
    const int E1 = in_sizes[1] / 2;   // 800000
    const int E3 = in_sizes[2] / 2;
    const int E9 = in_sizes[3] / 2;
    const int n3 = 3 * n;
    const int W  = (n + NB - 1) / NB; // 196 (< 512 -> 9-bit local id)

    const int nc1 = (E1 + CH - 1) / CH;
    const int nc2 = (E3 + CH - 1) / CH;
    const int nc3 = (E9 + CH - 1) / CH;
    const int nchunks = nc1 + nc2 + nc3;

    int* gcur    = (int*)d_ws;                           // TB
    unsigned int* pairBuf = (unsigned int*)(gcur + TB);  // TB*CAPE
    int* eidx    = (int*)(pairBuf + (size_t)TB * CAPE);  // TB*CAPE
    int* row_ptr = eidx + (size_t)TB * CAPE;             // 3n
    int* cnt     = row_ptr + n3;                         // 3n
    float* dinv  = (float*)(cnt + n3);                   // 3n
    float* h     = dinv + n3;                            // n*64
    float* x1    = h + (size_t)n * 64;                   // n*64
    float* x2    = x1 + (size_t)n * 64;                  // n*32

    // ---- CSR build (all 3 layers, 2 kernels) ----
    hipMemsetAsync(gcur, 0, TB * sizeof(int), stream);
    phase1<<<nchunks, P1T, 0, stream>>>(ei1, ei1 + E1, E1, ei3, ei3 + E3, E3,
                                        ei9, ei9 + E9, E9, nc1, nc2, W, gcur, pairBuf);
    phase2<<<TB, P2T, 0, stream>>>(pairBuf, gcur, n, W, row_ptr, cnt, dinv, eidx);

    const int gblk = (n + 63) / 64;

    // ---- layer 1: 64 -> 64 ----
    gemm_scale_kernel<64, 64><<<gblk, 256, 0, stream>>>(x0, W1, dinv, h, n);
    gather_kernel<64><<<(n + 15) / 16, 256, 0, stream>>>(row_ptr, cnt, eidx, dinv, h, b1, x1, n);

    // ---- layer 2: 64 -> 32 ----
    gemm_scale_kernel<64, 32><<<gblk, 256, 0, stream>>>(x1, W2, dinv + n, h, n);
    gather_kernel<32><<<(n + 31) / 32, 256, 0, stream>>>(row_ptr + n, cnt + n, eidx, dinv + n, h, b2, x2, n);

    // ---- layer 3: 32 -> 16 ----
    gemm_scale_kernel<32, 16><<<gblk, 256, 0, stream>>>(x2, W3, dinv + 2 * n, h, n);
    gather_kernel<16><<<(n + 63) / 64, 256, 0, stream>>>(row_ptr + 2 * n, cnt + 2 * n, eidx,
                                                         dinv + 2 * n, h, b3, (float*)d_out, n);
}